// Round 20
// baseline (84.234 us; speedup 1.0000x reference)
//
#include <hip/hip_runtime.h>

#define BATCH 16
#define TOK   4096
#define DIM   768
#define SMAX  128
#define BM    8     // segments (= MLP rows) per block

typedef float f32x4 __attribute__((ext_vector_type(4)));
typedef short s16x8 __attribute__((ext_vector_type(8)));

__device__ __forceinline__ int lower_bound_i(const int* __restrict__ a, int n, int v) {
    int lo = 0, hi = n;
    while (lo < hi) {
        int m = (lo + hi) >> 1;
        if (a[m] < v) lo = m + 1; else hi = m;
    }
    return lo;
}

__device__ __forceinline__ float f4get(const float4& v, int k) {
    switch (k) {
        case 0: return v.x;
        case 1: return v.y;
        case 2: return v.z;
        default: return v.w;
    }
}

// non-temporal float4 load: hit-if-present, no cache allocation on miss
__device__ __forceinline__ f32x4 nt4(const f32x4* p) {
    return __builtin_nontemporal_load(p);
}

// bf16 round-to-nearest-even (prep kernel, off hot path)
__device__ __forceinline__ unsigned short bf16_rne(float f) {
    unsigned int u = __float_as_uint(f);
    u += 0x7FFFu + ((u >> 16) & 1u);
    return (unsigned short)(u >> 16);
}

// pack two f32 -> bf16x2 (round-half-up)
__device__ __forceinline__ unsigned int bf16_pack2(float f0, float f1) {
    unsigned int u0 = __float_as_uint(f0) + 0x8000u;
    unsigned int u1 = __float_as_uint(f1) + 0x8000u;
    return (u0 >> 16) | (u1 & 0xFFFF0000u);
}

// Prep: W1 [768][384] f32 -> W1T [384][768] bf16 (RNE).
__global__ __launch_bounds__(768)
void prep_w1t_kernel(const float* __restrict__ W1, unsigned short* __restrict__ W1T) {
    const int c = blockIdx.x;     // 0..383
    const int k = threadIdx.x;    // 0..767
    W1T[c * 768 + k] = bf16_rne(W1[(size_t)k * 384 + c]);
}

// Kernel 0: precompute span boundaries (independent parallel searches).
__global__ __launch_bounds__(192)
void bounds_kernel(const int* __restrict__ seg, int* __restrict__ bounds) {
    const int b = blockIdx.x;
    const int s = threadIdx.x;
    if (s <= SMAX)
        bounds[b * (SMAX + 1) + s] = lower_bound_i(seg + b * TOK, TOK, s);
}

// Fused kernel (R16 structure; phase-A loads now NON-TEMPORAL).
// Phase A: per segment group (128 thr), two 64-lane halves split tokens by
// parity; lane owns 12 consecutive cols = 3 f32x4 NT loads (16 B/lane).
// h=1 partials via LDS scratch, h=0 combines and packs bf16 into padded
// A_bf [16][776]. Layer1 = mfma_f32_16x16x32_bf16 (verified, absmax 0.031).
// Layer2/3: fp32 k-split.
__global__ __launch_bounds__(1024)
void fused_kernel(const float* __restrict__ hidden,
                  const int* __restrict__ bounds,
                  const unsigned short* __restrict__ W1T, const float* __restrict__ b1,
                  const float* __restrict__ W2, const float* __restrict__ b2,
                  const float* __restrict__ W3, const float* __restrict__ b3,
                  float* __restrict__ out) {
    __shared__ __align__(16) unsigned int A_bf32[16 * 388]; // 16 rows x 776 bf16 = 24.8 KB
    __shared__ __align__(16) float X1[BM * 384];            // 12 KB
    __shared__ __align__(16) float X2[BM * 128];            //  4 KB
    __shared__ __align__(16) float P2[8 * BM * 128];        // 32 KB (phaseA scratch alias)

    const int tid  = threadIdx.x;
    const int row0 = blockIdx.x * BM;
    const int b    = row0 / SMAX;
    const int s0   = row0 % SMAX;
    const int grp  = tid >> 7;    // segment 0..7
    const int lane = tid & 127;
    const int h    = lane >> 6;   // token-parity half 0/1
    const int l6   = lane & 63;   // owns cols l6*12 .. l6*12+11

    // zero the padding rows 8-15 (read as A rows by MFMA; must be 0)
    for (int i = tid; i < 8 * 388; i += 1024)
        A_bf32[8 * 388 + i] = 0u;

    // ================= phase A: parity-split segment sums (NT loads) =========
    {
        const int lo = bounds[b * (SMAX + 1) + s0 + grp];
        const int hi = bounds[b * (SMAX + 1) + s0 + grp + 1];

        // f32x4 view: row has 192 float4; this lane's base = l6*3
        const f32x4* __restrict__ hp =
            reinterpret_cast<const f32x4*>(hidden + (size_t)b * TOK * DIM) + l6 * 3;

        f32x4 a0 = {0.f, 0.f, 0.f, 0.f};
        f32x4 a1 = {0.f, 0.f, 0.f, 0.f};
        f32x4 a2 = {0.f, 0.f, 0.f, 0.f};

        int t = lo + h;
        // 4 token-pairs deep: 12 independent NT float4 loads in flight
        for (; t + 8 <= hi; t += 8) {
            f32x4 v0[4], v1[4], v2[4];
            #pragma unroll
            for (int u = 0; u < 4; ++u) {
                const f32x4* p = hp + (size_t)(t + 2 * u) * 192;
                v0[u] = nt4(p + 0); v1[u] = nt4(p + 1); v2[u] = nt4(p + 2);
            }
            #pragma unroll
            for (int u = 0; u < 4; ++u) {
                a0 += v0[u]; a1 += v1[u]; a2 += v2[u];
            }
        }
        for (; t < hi; t += 2) {
            const f32x4* p = hp + (size_t)t * 192;
            a0 += nt4(p + 0); a1 += nt4(p + 1); a2 += nt4(p + 2);
        }

        // h=1 partials -> LDS scratch; h=0 combines (fixed order) and packs
        f32x4* scr = reinterpret_cast<f32x4*>(P2) + (grp * 64 + l6) * 3;
        if (h == 1) {
            scr[0] = a0; scr[1] = a1; scr[2] = a2;
        }
        __syncthreads();
        if (h == 0) {
            a0 += scr[0]; a1 += scr[1]; a2 += scr[2];
            const int base = grp * 388 + l6 * 6;
            A_bf32[base + 0] = bf16_pack2(a0.x, a0.y);
            A_bf32[base + 1] = bf16_pack2(a0.z, a0.w);
            A_bf32[base + 2] = bf16_pack2(a1.x, a1.y);
            A_bf32[base + 3] = bf16_pack2(a1.z, a1.w);
            A_bf32[base + 4] = bf16_pack2(a2.x, a2.y);
            A_bf32[base + 5] = bf16_pack2(a2.z, a2.w);
        }
    }
    __syncthreads();

    // ================= layer 1: MFMA (verified) =================
    {
        const int wid  = tid >> 6;    // wave 0..15
        const int l    = tid & 63;
        const int lrow = l & 15;      // A row / D col
        const int lg   = l >> 4;      // k-group 0..3

        if (wid < 12) {
            const int n0 = wid * 32;
            const int n1 = n0 + 16;
            f32x4 acc0 = {0.f, 0.f, 0.f, 0.f};
            f32x4 acc1 = {0.f, 0.f, 0.f, 0.f};

            const unsigned int* abase = &A_bf32[lrow * 388 + lg * 4];
            const unsigned short* w0p = W1T + (size_t)(n0 + lrow) * 768 + lg * 8;
            const unsigned short* w1p = W1T + (size_t)(n1 + lrow) * 768 + lg * 8;

            for (int ks = 0; ks < 24; ++ks) {
                s16x8 af  = *reinterpret_cast<const s16x8*>(abase + ks * 16);
                s16x8 bf0 = *reinterpret_cast<const s16x8*>(w0p + ks * 32);
                s16x8 bf1 = *reinterpret_cast<const s16x8*>(w1p + ks * 32);
                acc0 = __builtin_amdgcn_mfma_f32_16x16x32_bf16(af, bf0, acc0, 0, 0, 0);
                acc1 = __builtin_amdgcn_mfma_f32_16x16x32_bf16(af, bf1, acc1, 0, 0, 0);
            }

            if (lg < 2) {   // rows 0..7 real; lg 2,3 hold pad rows 8-15
                const int c0  = n0 + lrow;
                const int c1c = n1 + lrow;
                const float bb0 = b1[c0];
                const float bb1 = b1[c1c];
                #pragma unroll
                for (int r4 = 0; r4 < 4; ++r4) {
                    const int row = lg * 4 + r4;
                    const float v0 = acc0[r4] + bb0;
                    const float v1 = acc1[r4] + bb1;
                    X1[row * 384 + c0]  = v0 > 0.f ? v0 : 0.f;
                    X1[row * 384 + c1c] = v1 > 0.f ? v1 : 0.f;
                }
            }
        }
    }
    __syncthreads();

    // ================= layer 2: fp32 k-split =================
    const int c1 = lane;          // weight column within 128-group
    const int kg = grp;           // k-slice group 0..7
    {
        float acc2[BM];
        #pragma unroll
        for (int r = 0; r < BM; ++r) acc2[r] = 0.f;

        const int k0 = kg * 48;
        for (int k = k0; k < k0 + 48; k += 4) {
            float4 x[BM];
            #pragma unroll
            for (int r = 0; r < BM; ++r)
                x[r] = *reinterpret_cast<const float4*>(&X1[r * 384 + k]);
            #pragma unroll
            for (int kk = 0; kk < 4; ++kk) {
                const float w = W2[(size_t)(k + kk) * 128 + c1];
                #pragma unroll
                for (int r = 0; r < BM; ++r)
                    acc2[r] = fmaf(f4get(x[r], kk), w, acc2[r]);
            }
        }
        #pragma unroll
        for (int r = 0; r < BM; ++r)
            P2[(kg * BM + r) * 128 + c1] = acc2[r];
    }
    __syncthreads();

    // ---- reduce partials -> X2 (bias + relu) ----
    {
        const int row = grp;
        const int col = c1;
        float s = b2[col];
        #pragma unroll
        for (int g = 0; g < 8; ++g)
            s += P2[(g * BM + row) * 128 + col];
        X2[row * 128 + col] = s > 0.f ? s : 0.f;
    }
    __syncthreads();

    // ---- layer 3: 16 outputs ----
    if (tid < BM * 2) {
        const int r = tid >> 1;
        const int c = tid & 1;
        float sacc = 0.f;
        #pragma unroll 8
        for (int k = 0; k < 128; ++k)
            sacc = fmaf(X2[r * 128 + k], W3[k * 2 + c], sacc);
        out[(row0 + r) * 2 + c] = sacc + b3[c];
    }
}

extern "C" void kernel_launch(void* const* d_in, const int* in_sizes, int n_in,
                              void* d_out, int out_size, void* d_ws, size_t ws_size,
                              hipStream_t stream) {
    const float* hidden = (const float*)d_in[0];
    const int*   seg    = (const int*)d_in[1];
    const float* W1     = (const float*)d_in[2];
    const float* b1     = (const float*)d_in[3];
    const float* W2     = (const float*)d_in[4];
    const float* b2     = (const float*)d_in[5];
    const float* W3     = (const float*)d_in[6];
    const float* b3     = (const float*)d_in[7];
    float* out = (float*)d_out;

    int* bounds = (int*)d_ws;                                     // 8.3 KB
    unsigned short* W1T = (unsigned short*)((char*)d_ws + 16384); // 576 KB

    prep_w1t_kernel<<<384, 768, 0, stream>>>(W1, W1T);
    bounds_kernel<<<BATCH, 192, 0, stream>>>(seg, bounds);
    fused_kernel<<<(BATCH * SMAX) / BM, 1024, 0, stream>>>(
        hidden, bounds, W1T, b1, W2, b2, W3, b3, out);
}

// Round 23
// 66.081 us; speedup vs baseline: 1.2747x; 1.2747x over previous
//
#include <hip/hip_runtime.h>

#define BATCH 16
#define TOK   4096
#define DIM   768
#define SMAX  128
#define BM    8     // segments (= MLP rows) per block

typedef float f32x4 __attribute__((ext_vector_type(4)));
typedef short s16x8 __attribute__((ext_vector_type(8)));

__device__ __forceinline__ int lower_bound_i(const int* __restrict__ a, int n, int v) {
    int lo = 0, hi = n;
    while (lo < hi) {
        int m = (lo + hi) >> 1;
        if (a[m] < v) lo = m + 1; else hi = m;
    }
    return lo;
}

__device__ __forceinline__ float f4get(const float4& v, int k) {
    switch (k) {
        case 0: return v.x;
        case 1: return v.y;
        case 2: return v.z;
        default: return v.w;
    }
}

__device__ __forceinline__ void f4acc(float4& a, const float4& v) {
    a.x += v.x; a.y += v.y; a.z += v.z; a.w += v.w;
}

// bf16 round-to-nearest-even (prep kernel, off hot path)
__device__ __forceinline__ unsigned short bf16_rne(float f) {
    unsigned int u = __float_as_uint(f);
    u += 0x7FFFu + ((u >> 16) & 1u);
    return (unsigned short)(u >> 16);
}

// pack two f32 -> bf16x2 (round-half-up)
__device__ __forceinline__ unsigned int bf16_pack2(float f0, float f1) {
    unsigned int u0 = __float_as_uint(f0) + 0x8000u;
    unsigned int u1 = __float_as_uint(f1) + 0x8000u;
    return (u0 >> 16) | (u1 & 0xFFFF0000u);
}

// Prep: W1 [768][384] f32 -> W1T [384][768] bf16 (RNE).
__global__ __launch_bounds__(768)
void prep_w1t_kernel(const float* __restrict__ W1, unsigned short* __restrict__ W1T) {
    const int c = blockIdx.x;     // 0..383
    const int k = threadIdx.x;    // 0..767
    W1T[c * 768 + k] = bf16_rne(W1[(size_t)k * 384 + c]);
}

// Kernel 0: precompute span boundaries (independent parallel searches).
__global__ __launch_bounds__(192)
void bounds_kernel(const int* __restrict__ seg, int* __restrict__ bounds) {
    const int b = blockIdx.x;
    const int s = threadIdx.x;
    if (s <= SMAX)
        bounds[b * (SMAX + 1) + s] = lower_bound_i(seg + b * TOK, TOK, s);
}

// Fused kernel (R16 = best measured, 65.6 us). Phase A: per segment group
// (128 thr), two 64-lane halves split tokens by parity; lane owns 12
// consecutive cols = 3 float4 loads (16 B/lane). h=1 partials via LDS
// scratch, h=0 combines and packs bf16 into padded A_bf [16][776].
// Layer1 = mfma_f32_16x16x32_bf16 (verified, absmax 0.031).
// Layer2/3: fp32 k-split.
__global__ __launch_bounds__(1024)
void fused_kernel(const float* __restrict__ hidden,
                  const int* __restrict__ bounds,
                  const unsigned short* __restrict__ W1T, const float* __restrict__ b1,
                  const float* __restrict__ W2, const float* __restrict__ b2,
                  const float* __restrict__ W3, const float* __restrict__ b3,
                  float* __restrict__ out) {
    __shared__ __align__(16) unsigned int A_bf32[16 * 388]; // 16 rows x 776 bf16 = 24.8 KB
    __shared__ __align__(16) float X1[BM * 384];            // 12 KB
    __shared__ __align__(16) float X2[BM * 128];            //  4 KB
    __shared__ __align__(16) float P2[8 * BM * 128];        // 32 KB (phaseA scratch alias)

    const int tid  = threadIdx.x;
    const int row0 = blockIdx.x * BM;
    const int b    = row0 / SMAX;
    const int s0   = row0 % SMAX;
    const int grp  = tid >> 7;    // segment 0..7
    const int lane = tid & 127;
    const int h    = lane >> 6;   // token-parity half 0/1
    const int l6   = lane & 63;   // owns cols l6*12 .. l6*12+11

    // zero the padding rows 8-15 (read as A rows by MFMA; must be 0)
    for (int i = tid; i < 8 * 388; i += 1024)
        A_bf32[8 * 388 + i] = 0u;

    // ================= phase A: parity-split segment sums =================
    {
        const int lo = bounds[b * (SMAX + 1) + s0 + grp];
        const int hi = bounds[b * (SMAX + 1) + s0 + grp + 1];

        const float4* __restrict__ hp =
            reinterpret_cast<const float4*>(hidden + (size_t)b * TOK * DIM) + l6 * 3;

        float4 a0 = make_float4(0.f, 0.f, 0.f, 0.f);
        float4 a1 = make_float4(0.f, 0.f, 0.f, 0.f);
        float4 a2 = make_float4(0.f, 0.f, 0.f, 0.f);

        int t = lo + h;
        for (; t + 8 <= hi; t += 8) {
            float4 v0[4], v1[4], v2[4];
            #pragma unroll
            for (int u = 0; u < 4; ++u) {
                const float4* p = hp + (size_t)(t + 2 * u) * 192;
                v0[u] = p[0]; v1[u] = p[1]; v2[u] = p[2];
            }
            #pragma unroll
            for (int u = 0; u < 4; ++u) {
                f4acc(a0, v0[u]); f4acc(a1, v1[u]); f4acc(a2, v2[u]);
            }
        }
        for (; t < hi; t += 2) {
            const float4* p = hp + (size_t)t * 192;
            f4acc(a0, p[0]); f4acc(a1, p[1]); f4acc(a2, p[2]);
        }

        float4* scr = reinterpret_cast<float4*>(P2) + (grp * 64 + l6) * 3;
        if (h == 1) {
            scr[0] = a0; scr[1] = a1; scr[2] = a2;
        }
        __syncthreads();
        if (h == 0) {
            f4acc(a0, scr[0]); f4acc(a1, scr[1]); f4acc(a2, scr[2]);
            const int base = grp * 388 + l6 * 6;
            A_bf32[base + 0] = bf16_pack2(a0.x, a0.y);
            A_bf32[base + 1] = bf16_pack2(a0.z, a0.w);
            A_bf32[base + 2] = bf16_pack2(a1.x, a1.y);
            A_bf32[base + 3] = bf16_pack2(a1.z, a1.w);
            A_bf32[base + 4] = bf16_pack2(a2.x, a2.y);
            A_bf32[base + 5] = bf16_pack2(a2.z, a2.w);
        }
    }
    __syncthreads();

    // ================= layer 1: MFMA (verified) =================
    {
        const int wid  = tid >> 6;    // wave 0..15
        const int l    = tid & 63;
        const int lrow = l & 15;      // A row / D col
        const int lg   = l >> 4;      // k-group 0..3

        if (wid < 12) {
            const int n0 = wid * 32;
            const int n1 = n0 + 16;
            f32x4 acc0 = {0.f, 0.f, 0.f, 0.f};
            f32x4 acc1 = {0.f, 0.f, 0.f, 0.f};

            const unsigned int* abase = &A_bf32[lrow * 388 + lg * 4];
            const unsigned short* w0p = W1T + (size_t)(n0 + lrow) * 768 + lg * 8;
            const unsigned short* w1p = W1T + (size_t)(n1 + lrow) * 768 + lg * 8;

            for (int ks = 0; ks < 24; ++ks) {
                s16x8 af  = *reinterpret_cast<const s16x8*>(abase + ks * 16);
                s16x8 bf0 = *reinterpret_cast<const s16x8*>(w0p + ks * 32);
                s16x8 bf1 = *reinterpret_cast<const s16x8*>(w1p + ks * 32);
                acc0 = __builtin_amdgcn_mfma_f32_16x16x32_bf16(af, bf0, acc0, 0, 0, 0);
                acc1 = __builtin_amdgcn_mfma_f32_16x16x32_bf16(af, bf1, acc1, 0, 0, 0);
            }

            if (lg < 2) {   // rows 0..7 real; lg 2,3 hold pad rows 8-15
                const int c0  = n0 + lrow;
                const int c1c = n1 + lrow;
                const float bb0 = b1[c0];
                const float bb1 = b1[c1c];
                #pragma unroll
                for (int r4 = 0; r4 < 4; ++r4) {
                    const int row = lg * 4 + r4;
                    const float v0 = acc0[r4] + bb0;
                    const float v1 = acc1[r4] + bb1;
                    X1[row * 384 + c0]  = v0 > 0.f ? v0 : 0.f;
                    X1[row * 384 + c1c] = v1 > 0.f ? v1 : 0.f;
                }
            }
        }
    }
    __syncthreads();

    // ================= layer 2: fp32 k-split =================
    const int c1 = lane;          // weight column within 128-group
    const int kg = grp;           // k-slice group 0..7
    {
        float acc2[BM];
        #pragma unroll
        for (int r = 0; r < BM; ++r) acc2[r] = 0.f;

        const int k0 = kg * 48;
        for (int k = k0; k < k0 + 48; k += 4) {
            float4 x[BM];
            #pragma unroll
            for (int r = 0; r < BM; ++r)
                x[r] = *reinterpret_cast<const float4*>(&X1[r * 384 + k]);
            #pragma unroll
            for (int kk = 0; kk < 4; ++kk) {
                const float w = W2[(size_t)(k + kk) * 128 + c1];
                #pragma unroll
                for (int r = 0; r < BM; ++r)
                    acc2[r] = fmaf(f4get(x[r], kk), w, acc2[r]);
            }
        }
        #pragma unroll
        for (int r = 0; r < BM; ++r)
            P2[(kg * BM + r) * 128 + c1] = acc2[r];
    }
    __syncthreads();

    // ---- reduce partials -> X2 (bias + relu) ----
    {
        const int row = grp;
        const int col = c1;
        float s = b2[col];
        #pragma unroll
        for (int g = 0; g < 8; ++g)
            s += P2[(g * BM + row) * 128 + col];
        X2[row * 128 + col] = s > 0.f ? s : 0.f;
    }
    __syncthreads();

    // ---- layer 3: 16 outputs ----
    if (tid < BM * 2) {
        const int r = tid >> 1;
        const int c = tid & 1;
        float sacc = 0.f;
        #pragma unroll 8
        for (int k = 0; k < 128; ++k)
            sacc = fmaf(X2[r * 128 + k], W3[k * 2 + c], sacc);
        out[(row0 + r) * 2 + c] = sacc + b3[c];
    }
}

extern "C" void kernel_launch(void* const* d_in, const int* in_sizes, int n_in,
                              void* d_out, int out_size, void* d_ws, size_t ws_size,
                              hipStream_t stream) {
    const float* hidden = (const float*)d_in[0];
    const int*   seg    = (const int*)d_in[1];
    const float* W1     = (const float*)d_in[2];
    const float* b1     = (const float*)d_in[3];
    const float* W2     = (const float*)d_in[4];
    const float* b2     = (const float*)d_in[5];
    const float* W3     = (const float*)d_in[6];
    const float* b3     = (const float*)d_in[7];
    float* out = (float*)d_out;

    int* bounds = (int*)d_ws;                                     // 8.3 KB
    unsigned short* W1T = (unsigned short*)((char*)d_ws + 16384); // 576 KB

    prep_w1t_kernel<<<384, 768, 0, stream>>>(W1, W1T);
    bounds_kernel<<<BATCH, 192, 0, stream>>>(seg, bounds);
    fused_kernel<<<(BATCH * SMAX) / BM, 1024, 0, stream>>>(
        hidden, bounds, W1T, b1, W2, b2, W3, b3, out);
}